// Round 3
// baseline (1894.987 us; speedup 1.0000x reference)
//
#include <hip/hip_runtime.h>
#include <stdint.h>

#define Bsz 4
#define Tsz 2048
#define Dsz 512
#define Hsz 8
#define HDsz 4096
#define Msz 8192
#define SCALE 0.044194173824159216f

typedef __attribute__((ext_vector_type(8))) short bf16x8;
typedef __attribute__((ext_vector_type(4))) float f32x4;
typedef __attribute__((ext_vector_type(4))) short s16x4;

static __device__ __forceinline__ short f2bf(float x) {
    uint32_t b = __float_as_uint(x);
    b += 0x7fff + ((b >> 16) & 1);
    return (short)(b >> 16);
}

// ---------------- Kernel A: X fp32 -> bf16 cast (query & value) -------------
__global__ __launch_bounds__(256) void xcast_kernel(
    const float* __restrict__ Xq, const float* __restrict__ Xv,
    short* __restrict__ Oq, short* __restrict__ Ov)
{
    int idx = blockIdx.x * 256 + threadIdx.x;          // 0 .. 2*1048576-1
    const float* src = (idx < 1048576) ? Xq : Xv;
    short* dst = (idx < 1048576) ? Oq : Ov;
    int i = (idx < 1048576) ? idx : idx - 1048576;
    float4 v = *(const float4*)&src[(size_t)i * 4];
    s16x4 o;
    o.x = f2bf(v.x); o.y = f2bf(v.y); o.z = f2bf(v.z); o.w = f2bf(v.w);
    *(s16x4*)&dst[(size_t)i * 4] = o;
}

// ---------------- Kernel 0: weight transpose + bf16 convert -----------------
__global__ __launch_bounds__(256) void wtrans_kernel(
    const float* __restrict__ Wq, const float* __restrict__ Wk,
    const float* __restrict__ Wv, short* __restrict__ WtAll)
{
    const float* W = (blockIdx.z == 0) ? Wq : (blockIdx.z == 1) ? Wk : Wv;
    short* Wt = WtAll + (size_t)blockIdx.z * (size_t)HDsz * Dsz;
    __shared__ float tile[32][33];
    int tx = threadIdx.x, ty = threadIdx.y;
    int k0 = blockIdx.x * 32, n0 = blockIdx.y * 32;
    for (int i = 0; i < 4; i++)
        tile[ty + i * 8][tx] = W[(size_t)(k0 + ty + i * 8) * HDsz + n0 + tx];
    __syncthreads();
    for (int i = 0; i < 4; i++)
        Wt[(size_t)(n0 + ty + i * 8) * Dsz + k0 + tx] = f2bf(tile[tx][ty + i * 8]);
}

// ---------------- Kernel 1: fused QKV projection GEMM (v3) ------------------
// A = Xbf [8192][512] bf16, B = Wt [4096][512] bf16. 128x128 tile, BK=32.
__global__ __launch_bounds__(256, 3) void proj_gemm_kernel(
    const short* __restrict__ Xqb, const short* __restrict__ Xvb,
    const short* __restrict__ WtAll, const float* __restrict__ bq,
    const float* __restrict__ bk, const float* __restrict__ bv,
    short* __restrict__ Qo, short* __restrict__ Ko, short* __restrict__ Vto)
{
    const int mode = blockIdx.z;
    const short* X = (mode == 0) ? Xqb : Xvb;
    const short* Wt = WtAll + (size_t)mode * (size_t)HDsz * Dsz;
    const float* bias = (mode == 0) ? bq : (mode == 1) ? bk : bv;
    const int m0 = blockIdx.x * 128, n0 = blockIdx.y * 128;

    __shared__ short sm[17408];

    const int tid = threadIdx.x;
    const int lane = tid & 63, wave = tid >> 6;
    const int quad = lane >> 4, l16 = lane & 15;
    const int wm = wave >> 1, wn = wave & 1;

    const int dmarow = lane >> 2;
    const int dmachunk = (lane & 3) ^ ((lane >> 3) & 3);
    const int rdsw = (quad ^ ((l16 >> 1) & 3)) * 8;   // fragment-read swizzle

    f32x4 acc[4][4];
    for (int i = 0; i < 4; i++)
        for (int j = 0; j < 4; j++)
            acc[i][j] = f32x4{0.f, 0.f, 0.f, 0.f};

#define STAGE(ksv, bufsel) do {                                                  \
        const int _ks = (ksv);                                                   \
        short* _A = sm + (bufsel) * 4096;                                        \
        short* _B = sm + 8192 + (bufsel) * 4096;                                 \
        for (int s = 0; s < 2; s++) {                                            \
            int c = wave * 2 + s;                                                \
            int row = c * 16 + dmarow;                                           \
            const short* ga = X + (size_t)(m0 + row) * Dsz + _ks + dmachunk * 8; \
            __builtin_amdgcn_global_load_lds(                                    \
                (const __attribute__((address_space(1))) void*)ga,               \
                (__attribute__((address_space(3))) void*)&_A[c * 512], 16, 0, 0);\
            const short* gb = Wt + (size_t)(n0 + row) * Dsz + _ks + dmachunk * 8;\
            __builtin_amdgcn_global_load_lds(                                    \
                (const __attribute__((address_space(1))) void*)gb,               \
                (__attribute__((address_space(3))) void*)&_B[c * 512], 16, 0, 0);\
        }                                                                        \
    } while (0)

    STAGE(0, 0);
    __syncthreads();

    for (int t = 0; t < 16; t++) {
        const int cur = t & 1;
        if (t < 15) STAGE((t + 1) * 32, cur ^ 1);   // prefetch overlaps compute
        const short* Ac = sm + cur * 4096;
        const short* Bc = sm + 8192 + cur * 4096;
        bf16x8 af[4], bfr[4];
        for (int i = 0; i < 4; i++)
            af[i] = *(const bf16x8*)&Ac[(wm * 64 + i * 16 + l16) * 32 + rdsw];
        for (int j = 0; j < 4; j++)
            bfr[j] = *(const bf16x8*)&Bc[(wn * 64 + j * 16 + l16) * 32 + rdsw];
        for (int i = 0; i < 4; i++)
            for (int j = 0; j < 4; j++)
                acc[i][j] = __builtin_amdgcn_mfma_f32_16x16x32_bf16(
                    af[i], bfr[j], acc[i][j], 0, 0, 0);
        __syncthreads();   // drains DMA(t+1) + protects buffer reuse
    }
#undef STAGE

    // ---- epilogue: stage C tile in LDS, then coalesced bf16x8 stores ----
    const int b = m0 >> 11, t0 = m0 & 2047;          // m-range is within one b
    const int h = n0 >> 9, d0 = n0 & 511;            // n-range is within one h
    const float scv = (mode == 0) ? SCALE : 1.0f;

    if (mode == 2) {
        // store transposed into LDS: C[d][t]
        for (int i = 0; i < 4; i++)
            for (int j = 0; j < 4; j++) {
                int c = wn * 64 + j * 16 + l16;
                float bb = bias[n0 + c];
                int rb = wm * 64 + i * 16 + quad * 4;
                for (int r = 0; r < 4; r++)
                    sm[c * 136 + rb + r] = f2bf(acc[i][j][r] + bb);
            }
    } else {
        // C[t][d]
        for (int i = 0; i < 4; i++)
            for (int j = 0; j < 4; j++) {
                int c = wn * 64 + j * 16 + l16;
                float bb = bias[n0 + c];
                int rb = wm * 64 + i * 16 + quad * 4;
                for (int r = 0; r < 4; r++)
                    sm[(rb + r) * 136 + c] = f2bf((acc[i][j][r] + bb) * scv);
            }
    }
    __syncthreads();

    if (mode == 2) {
        // Vt layout [bh][d][t]: contiguous along t
        size_t base = ((size_t)(b * Hsz + h) * Dsz + d0) * Tsz + t0;
        for (int k = 0; k < 8; k++) {
            int cid = k * 256 + tid;
            int c = cid >> 4, r8 = (cid & 15) * 8;
            *(bf16x8*)&Vto[base + (size_t)c * Tsz + r8] =
                *(const bf16x8*)&sm[c * 136 + r8];
        }
    } else {
        short* O = (mode == 0) ? Qo : Ko;
        size_t base = ((size_t)(b * Hsz + h) * Tsz + t0) * Dsz + d0;
        for (int k = 0; k < 8; k++) {
            int cid = k * 256 + tid;
            int r = cid >> 4, c8 = (cid & 15) * 8;
            *(bf16x8*)&O[base + (size_t)r * Dsz + c8] =
                *(const bf16x8*)&sm[r * 136 + c8];
        }
    }
}

// ---------------- Kernel 2: causal flash attention (v5) ---------------------
// Structural changes vs v4 (284us, 1 block/CU, 41% CU imbalance):
//  - Balanced-by-construction blocks: block i owns q-subtiles i AND 31-i
//    (64 rows each; waves 0-3 = low, waves 4-7 = high). Every block does
//    exactly 33 subtile-kv units -> no dispatch-order assumptions needed.
//  - V no longer LDS-staged: D-split PV reads V once per tile per group as
//    coalesced bf16x8 global loads (L2/L3 resident). LDS 158.7KB -> 76.8KB
//    -> 2 blocks/CU, so barrier stalls are hidden by the co-resident block.
// Math path identical to v4 (same MFMA/exp/accum order) -> same absmax.
__global__ __launch_bounds__(512, 4) void attn_kernel(
    const short* __restrict__ Q, const short* __restrict__ K,
    const short* __restrict__ Vt, float* __restrict__ out)
{
    extern __shared__ short smem[];
    // layout (shorts): K0 @0 (32x520), K1 @16640, P @33280 (8 waves x 16 x 40)

    const int bid = blockIdx.x;
    const int ib = bid >> 5;                   // 0..15 : subtile-pair index
    const int bh = bid & 31;
    const short* Qb = Q + (size_t)bh * Tsz * Dsz;
    const short* Kb = K + (size_t)bh * Tsz * Dsz;
    const short* Vb = Vt + (size_t)bh * Dsz * Tsz;

    const int tid = threadIdx.x;
    const int lane = tid & 63, wave = tid >> 6;
    const int quad = lane >> 4, l16 = lane & 15;
    const int g = wave >> 2;                   // 0 = low subtile, 1 = high
    const int ws = wave & 3;                   // wave-in-group: QK rows + D-slice
    const int sr = (g == 0) ? ib * 64 : (31 - ib) * 64;   // subtile row base
    const int qw = sr + ws * 16;               // this wave's 16 QK rows
    short* Pw = smem + 33280 + wave * 640;

    // Q fragments resident (16 ksteps x 8 bf16 = 64 VGPRs)
    bf16x8 qf[16];
    for (int ks = 0; ks < 16; ks++)
        qf[ks] = *(const bf16x8*)&Qb[(size_t)(qw + l16) * Dsz + ks * 32 + quad * 8];

    // acc[rf*8+df]: rows sr + rf*16 + quad*4 + r, dims ws*128 + df*16 + l16
    f32x4 acc[32];
    for (int i = 0; i < 32; i++) acc[i] = f32x4{0.f, 0.f, 0.f, 0.f};
    float lacc[4] = {0.f, 0.f, 0.f, 0.f};

    // prologue: K tile 0 -> buffer 0
    for (int i = 0; i < 4; i++) {
        int r = wave * 4 + i;
        const short* gp = Kb + (size_t)r * Dsz + lane * 8;
        __builtin_amdgcn_global_load_lds(
            (const __attribute__((address_space(1))) void*)gp,
            (__attribute__((address_space(3))) void*)&smem[r * 520], 16, 0, 0);
    }
    __syncthreads();

    const int nkv = 2 * (32 - ib);             // kv-tiles covering the high subtile
    for (int kt = 0; kt < nkv; kt++) {
        const int kv0 = kt * 32;
        short* Ksc = smem + (kt & 1) * 16640;

        // ---- prefetch K(t+1) via DMA (overlaps QK below) ----
        if (kt + 1 < nkv) {
            short* Ksn = smem + ((kt + 1) & 1) * 16640;
            for (int i = 0; i < 4; i++) {
                int r = wave * 4 + i;
                const short* gp = Kb + (size_t)(kv0 + 32 + r) * Dsz + lane * 8;
                __builtin_amdgcn_global_load_lds(
                    (const __attribute__((address_space(1))) void*)gp,
                    (__attribute__((address_space(3))) void*)&Ksn[r * 520], 16, 0, 0);
            }
        }

        const bool qact = (kv0 <= qw + 15);
        const bool pvact = (kv0 <= sr + 63);

        // ---- QK^T for this wave's 16 rows ----
        f32x4 s0 = f32x4{0.f, 0.f, 0.f, 0.f}, s1 = f32x4{0.f, 0.f, 0.f, 0.f};
        if (qact) {
            for (int ks = 0; ks < 16; ks++) {
                bf16x8 b0 = *(const bf16x8*)&Ksc[l16 * 520 + ks * 32 + quad * 8];
                bf16x8 b1 = *(const bf16x8*)&Ksc[(16 + l16) * 520 + ks * 32 + quad * 8];
                s0 = __builtin_amdgcn_mfma_f32_16x16x32_bf16(qf[ks], b0, s0, 0, 0, 0);
                s1 = __builtin_amdgcn_mfma_f32_16x16x32_bf16(qf[ks], b1, s1, 0, 0, 0);
            }
        }

        // ---- V(t) loads from global (L2/L3), latency hidden by softmax+bar ----
        bf16x8 vb[8];
        if (pvact) {
            for (int df = 0; df < 8; df++)
                vb[df] = *(const bf16x8*)
                    &Vb[(size_t)(ws * 128 + df * 16 + l16) * Tsz + kv0 + quad * 8];
        }

        // ---- softmax + P write ----
        if (qact) {
            bool full = (kv0 + 31 <= qw);
            for (int r = 0; r < 4; r++) {
                int rowg = qw + quad * 4 + r;
                float p0 = __expf(fminf(s0[r], 40.f));
                float p1 = __expf(fminf(s1[r], 40.f));
                if (!full) {
                    if (kv0 + l16 > rowg) p0 = 0.f;
                    if (kv0 + 16 + l16 > rowg) p1 = 0.f;
                }
                lacc[r] += p0 + p1;
                Pw[(quad * 4 + r) * 40 + l16] = f2bf(p0);
                Pw[(quad * 4 + r) * 40 + 16 + l16] = f2bf(p1);
            }
        }
        __syncthreads();   // P visible to the group; also drains K-DMA(t+1)

        // ---- PV: D-split within group; V from registers, P from LDS ----
        if (pvact) {
            for (int rf = 0; rf < 4; rf++) {
                if (kv0 <= sr + rf * 16 + 15) {
                    bf16x8 pa = *(const bf16x8*)
                        &smem[33280 + (g * 4 + rf) * 640 + l16 * 40 + quad * 8];
                    for (int df = 0; df < 8; df++)
                        acc[rf * 8 + df] = __builtin_amdgcn_mfma_f32_16x16x32_bf16(
                            pa, vb[df], acc[rf * 8 + df], 0, 0, 0);
                }
            }
        }
        __syncthreads();   // protect P before next tile's writes
    }

    // epilogue: share per-row denominators via LDS (reuses P region)
    float* lsh = (float*)(smem + 33280);
    for (int r = 0; r < 4; r++) {
        float l = lacc[r];
        l += __shfl_xor(l, 1);
        l += __shfl_xor(l, 2);
        l += __shfl_xor(l, 4);
        l += __shfl_xor(l, 8);
        if (l16 == 0) lsh[wave * 16 + quad * 4 + r] = l;
    }
    __syncthreads();

    const int b = bh >> 3, h = bh & 7;
    for (int rf = 0; rf < 4; rf++) {
        for (int r = 0; r < 4; r++) {
            float invl = 1.0f / lsh[(g * 4 + rf) * 16 + quad * 4 + r];
            int t = sr + rf * 16 + quad * 4 + r;
            float* op = &out[(size_t)(b * Tsz + t) * HDsz + h * Dsz
                             + ws * 128 + l16];
            for (int df = 0; df < 8; df++)
                op[df * 16] = acc[rf * 8 + df][r] * invl;
        }
    }
}

extern "C" void kernel_launch(void* const* d_in, const int* in_sizes, int n_in,
                              void* d_out, int out_size, void* d_ws, size_t ws_size,
                              hipStream_t stream) {
    const float* query = (const float*)d_in[0];
    const float* value = (const float*)d_in[1];
    const float* Wq = (const float*)d_in[2];
    const float* bq = (const float*)d_in[3];
    const float* Wk = (const float*)d_in[4];
    const float* bk = (const float*)d_in[5];
    const float* Wv = (const float*)d_in[6];
    const float* bv = (const float*)d_in[7];
    float* out = (float*)d_out;

    char* ws = (char*)d_ws;
    short* Wt  = (short*)ws;                        // 12,582,912 B
    short* Xqb = (short*)(ws + 12582912);           //  8,388,608 B
    short* Xvb = (short*)(ws + 20971520);           //  8,388,608 B
    short* Qb  = (short*)(ws + 29360128);           // 67,108,864 B
    short* Kb  = (short*)(ws + 96468992);           // 67,108,864 B
    short* Vtb = (short*)(ws + 163577856);          // 67,108,864 B (end 230.7MB)

    (void)hipFuncSetAttribute((const void*)attn_kernel,
                        hipFuncAttributeMaxDynamicSharedMemorySize, 76800);

    xcast_kernel<<<8192, 256, 0, stream>>>(query, value, Xqb, Xvb);
    wtrans_kernel<<<dim3(16, 128, 3), dim3(32, 8), 0, stream>>>(Wq, Wk, Wv, Wt);
    proj_gemm_kernel<<<dim3(64, 32, 3), 256, 0, stream>>>(
        Xqb, Xvb, Wt, bq, bk, bv, Qb, Kb, Vtb);
    attn_kernel<<<dim3(512), dim3(512), 76800, stream>>>(Qb, Kb, Vtb, out);
}

// Round 4
// 669.352 us; speedup vs baseline: 2.8311x; 2.8311x over previous
//
#include <hip/hip_runtime.h>
#include <stdint.h>

#define Bsz 4
#define Tsz 2048
#define Dsz 512
#define Hsz 8
#define HDsz 4096
#define Msz 8192
#define SCALE 0.044194173824159216f

typedef __attribute__((ext_vector_type(8))) short bf16x8;
typedef __attribute__((ext_vector_type(4))) float f32x4;
typedef __attribute__((ext_vector_type(4))) short s16x4;

static __device__ __forceinline__ short f2bf(float x) {
    uint32_t b = __float_as_uint(x);
    b += 0x7fff + ((b >> 16) & 1);
    return (short)(b >> 16);
}

// ---------------- Kernel A: X fp32 -> bf16 cast (query & value) -------------
__global__ __launch_bounds__(256) void xcast_kernel(
    const float* __restrict__ Xq, const float* __restrict__ Xv,
    short* __restrict__ Oq, short* __restrict__ Ov)
{
    int idx = blockIdx.x * 256 + threadIdx.x;          // 0 .. 2*1048576-1
    const float* src = (idx < 1048576) ? Xq : Xv;
    short* dst = (idx < 1048576) ? Oq : Ov;
    int i = (idx < 1048576) ? idx : idx - 1048576;
    float4 v = *(const float4*)&src[(size_t)i * 4];
    s16x4 o;
    o.x = f2bf(v.x); o.y = f2bf(v.y); o.z = f2bf(v.z); o.w = f2bf(v.w);
    *(s16x4*)&dst[(size_t)i * 4] = o;
}

// ---------------- Kernel 0: weight transpose + bf16 convert -----------------
__global__ __launch_bounds__(256) void wtrans_kernel(
    const float* __restrict__ Wq, const float* __restrict__ Wk,
    const float* __restrict__ Wv, short* __restrict__ WtAll)
{
    const float* W = (blockIdx.z == 0) ? Wq : (blockIdx.z == 1) ? Wk : Wv;
    short* Wt = WtAll + (size_t)blockIdx.z * (size_t)HDsz * Dsz;
    __shared__ float tile[32][33];
    int tx = threadIdx.x, ty = threadIdx.y;
    int k0 = blockIdx.x * 32, n0 = blockIdx.y * 32;
    for (int i = 0; i < 4; i++)
        tile[ty + i * 8][tx] = W[(size_t)(k0 + ty + i * 8) * HDsz + n0 + tx];
    __syncthreads();
    for (int i = 0; i < 4; i++)
        Wt[(size_t)(n0 + ty + i * 8) * Dsz + k0 + tx] = f2bf(tile[tx][ty + i * 8]);
}

// ---------------- Kernel 1: fused QKV projection GEMM (round-1 config) ------
// A = Xbf [8192][512] bf16, B = Wt [4096][512] bf16. 128x128 tile, BK=32.
__global__ __launch_bounds__(256, 2) void proj_gemm_kernel(
    const short* __restrict__ Xqb, const short* __restrict__ Xvb,
    const short* __restrict__ WtAll, const float* __restrict__ bq,
    const float* __restrict__ bk, const float* __restrict__ bv,
    short* __restrict__ Qo, short* __restrict__ Ko, short* __restrict__ Vto)
{
    const int mode = blockIdx.z;
    const short* X = (mode == 0) ? Xqb : Xvb;
    const short* Wt = WtAll + (size_t)mode * (size_t)HDsz * Dsz;
    const float* bias = (mode == 0) ? bq : (mode == 1) ? bk : bv;
    const int m0 = blockIdx.x * 128, n0 = blockIdx.y * 128;

    __shared__ short sm[17408];

    const int tid = threadIdx.x;
    const int lane = tid & 63, wave = tid >> 6;
    const int quad = lane >> 4, l16 = lane & 15;
    const int wm = wave >> 1, wn = wave & 1;

    const int dmarow = lane >> 2;
    const int dmachunk = (lane & 3) ^ ((lane >> 3) & 3);
    const int rdsw = (quad ^ ((l16 >> 1) & 3)) * 8;   // fragment-read swizzle

    f32x4 acc[4][4];
    for (int i = 0; i < 4; i++)
        for (int j = 0; j < 4; j++)
            acc[i][j] = f32x4{0.f, 0.f, 0.f, 0.f};

#define STAGE(ksv, bufsel) do {                                                  \
        const int _ks = (ksv);                                                   \
        short* _A = sm + (bufsel) * 4096;                                        \
        short* _B = sm + 8192 + (bufsel) * 4096;                                 \
        for (int s = 0; s < 2; s++) {                                            \
            int c = wave * 2 + s;                                                \
            int row = c * 16 + dmarow;                                           \
            const short* ga = X + (size_t)(m0 + row) * Dsz + _ks + dmachunk * 8; \
            __builtin_amdgcn_global_load_lds(                                    \
                (const __attribute__((address_space(1))) void*)ga,               \
                (__attribute__((address_space(3))) void*)&_A[c * 512], 16, 0, 0);\
            const short* gb = Wt + (size_t)(n0 + row) * Dsz + _ks + dmachunk * 8;\
            __builtin_amdgcn_global_load_lds(                                    \
                (const __attribute__((address_space(1))) void*)gb,               \
                (__attribute__((address_space(3))) void*)&_B[c * 512], 16, 0, 0);\
        }                                                                        \
    } while (0)

    STAGE(0, 0);
    __syncthreads();

    for (int t = 0; t < 16; t++) {
        const int cur = t & 1;
        if (t < 15) STAGE((t + 1) * 32, cur ^ 1);   // prefetch overlaps compute
        const short* Ac = sm + cur * 4096;
        const short* Bc = sm + 8192 + cur * 4096;
        bf16x8 af[4], bfr[4];
        for (int i = 0; i < 4; i++)
            af[i] = *(const bf16x8*)&Ac[(wm * 64 + i * 16 + l16) * 32 + rdsw];
        for (int j = 0; j < 4; j++)
            bfr[j] = *(const bf16x8*)&Bc[(wn * 64 + j * 16 + l16) * 32 + rdsw];
        for (int i = 0; i < 4; i++)
            for (int j = 0; j < 4; j++)
                acc[i][j] = __builtin_amdgcn_mfma_f32_16x16x32_bf16(
                    af[i], bfr[j], acc[i][j], 0, 0, 0);
        __syncthreads();   // drains DMA(t+1) + protects buffer reuse
    }
#undef STAGE

    // ---- epilogue: stage C tile in LDS, then coalesced bf16x8 stores ----
    const int b = m0 >> 11, t0 = m0 & 2047;          // m-range is within one b
    const int h = n0 >> 9, d0 = n0 & 511;            // n-range is within one h
    const float scv = (mode == 0) ? SCALE : 1.0f;

    if (mode == 2) {
        // store transposed into LDS: C[d][t]
        for (int i = 0; i < 4; i++)
            for (int j = 0; j < 4; j++) {
                int c = wn * 64 + j * 16 + l16;
                float bb = bias[n0 + c];
                int rb = wm * 64 + i * 16 + quad * 4;
                for (int r = 0; r < 4; r++)
                    sm[c * 136 + rb + r] = f2bf(acc[i][j][r] + bb);
            }
    } else {
        // C[t][d]
        for (int i = 0; i < 4; i++)
            for (int j = 0; j < 4; j++) {
                int c = wn * 64 + j * 16 + l16;
                float bb = bias[n0 + c];
                int rb = wm * 64 + i * 16 + quad * 4;
                for (int r = 0; r < 4; r++)
                    sm[(rb + r) * 136 + c] = f2bf((acc[i][j][r] + bb) * scv);
            }
    }
    __syncthreads();

    if (mode == 2) {
        // Vt layout [bh][d][t]: contiguous along t
        size_t base = ((size_t)(b * Hsz + h) * Dsz + d0) * Tsz + t0;
        for (int k = 0; k < 8; k++) {
            int cid = k * 256 + tid;
            int c = cid >> 4, r8 = (cid & 15) * 8;
            *(bf16x8*)&Vto[base + (size_t)c * Tsz + r8] =
                *(const bf16x8*)&sm[c * 136 + r8];
        }
    } else {
        short* O = (mode == 0) ? Qo : Ko;
        size_t base = ((size_t)(b * Hsz + h) * Tsz + t0) * Dsz + d0;
        for (int k = 0; k < 8; k++) {
            int cid = k * 256 + tid;
            int r = cid >> 4, c8 = (cid & 15) * 8;
            *(bf16x8*)&O[base + (size_t)r * Dsz + c8] =
                *(const bf16x8*)&sm[r * 136 + c8];
        }
    }
}

// ---------------- Kernel 2: causal flash attention (v6) ---------------------
// v5's verified-correct logic (paired subtiles, D-split PV, V from global)
// with the register budget FIXED: 256-thread blocks (4 waves), two sequential
// 64-row passes (subtile ib then 31-ib -> uniform 66 kv-iters per block).
// __launch_bounds__(256,2): 2 waves/SIMD -> 256-reg cap (need ~250, no spill),
// 2 blocks/CU resident (LDS 71.9KB). v5's (512,4) capped at 128 regs -> 7GB
// of scratch traffic; this keeps acc[32]+qf[16]+vb[8] in registers.
__global__ __launch_bounds__(256, 2) void attn_kernel(
    const short* __restrict__ Q, const short* __restrict__ K,
    const short* __restrict__ Vt, float* __restrict__ out)
{
    extern __shared__ short smem[];
    // shorts: K0 @0 (32x520), K1 @16640, P @33280 (4x640), lsh @35840 (128)

    const int bid = blockIdx.x;
    const int ib = bid >> 5;                   // 0..15 : subtile-pair index
    const int bh = bid & 31;
    const short* Qb = Q + (size_t)bh * Tsz * Dsz;
    const short* Kb = K + (size_t)bh * Tsz * Dsz;
    const short* Vb = Vt + (size_t)bh * Dsz * Tsz;

    const int tid = threadIdx.x;
    const int lane = tid & 63, wave = tid >> 6;       // 4 waves
    const int quad = lane >> 4, l16 = lane & 15;
    short* Pw = smem + 33280 + wave * 640;
    const int b = bh >> 3, h = bh & 7;

    for (int pass = 0; pass < 2; pass++) {
        const int sr = (pass == 0) ? ib * 64 : (31 - ib) * 64;   // 64-row subtile
        const int qw = sr + wave * 16;                           // wave's QK rows

        // Q fragments resident (16 ksteps x 8 bf16 = 64 VGPRs)
        bf16x8 qf[16];
#pragma unroll
        for (int ks = 0; ks < 16; ks++)
            qf[ks] = *(const bf16x8*)&Qb[(size_t)(qw + l16) * Dsz + ks * 32 + quad * 8];

        // acc[rf*8+df]: rows sr+rf*16+quad*4+r, dims wave*128+df*16+l16
        f32x4 acc[32];
#pragma unroll
        for (int i = 0; i < 32; i++) acc[i] = f32x4{0.f, 0.f, 0.f, 0.f};
        float lacc[4] = {0.f, 0.f, 0.f, 0.f};

        // prologue: K tile 0 -> buffer 0 (8 rows per wave)
#pragma unroll
        for (int i = 0; i < 8; i++) {
            int r = wave * 8 + i;
            const short* gp = Kb + (size_t)r * Dsz + lane * 8;
            __builtin_amdgcn_global_load_lds(
                (const __attribute__((address_space(1))) void*)gp,
                (__attribute__((address_space(3))) void*)&smem[r * 520], 16, 0, 0);
        }
        __syncthreads();

        const int nkv = sr / 32 + 2;           // kv-tiles covering rows sr..sr+63
        for (int kt = 0; kt < nkv; kt++) {
            const int kv0 = kt * 32;
            short* Ksc = smem + (kt & 1) * 16640;

            // ---- prefetch K(t+1) via DMA (overlaps QK below) ----
            if (kt + 1 < nkv) {
                short* Ksn = smem + ((kt + 1) & 1) * 16640;
#pragma unroll
                for (int i = 0; i < 8; i++) {
                    int r = wave * 8 + i;
                    const short* gp = Kb + (size_t)(kv0 + 32 + r) * Dsz + lane * 8;
                    __builtin_amdgcn_global_load_lds(
                        (const __attribute__((address_space(1))) void*)gp,
                        (__attribute__((address_space(3))) void*)&Ksn[r * 520], 16, 0, 0);
                }
            }

            const bool qact = (kv0 <= qw + 15);

            // ---- QK^T for this wave's 16 rows ----
            f32x4 s0 = f32x4{0.f, 0.f, 0.f, 0.f}, s1 = f32x4{0.f, 0.f, 0.f, 0.f};
            if (qact) {
#pragma unroll
                for (int ks = 0; ks < 16; ks++) {
                    bf16x8 b0 = *(const bf16x8*)&Ksc[l16 * 520 + ks * 32 + quad * 8];
                    bf16x8 b1 = *(const bf16x8*)&Ksc[(16 + l16) * 520 + ks * 32 + quad * 8];
                    s0 = __builtin_amdgcn_mfma_f32_16x16x32_bf16(qf[ks], b0, s0, 0, 0, 0);
                    s1 = __builtin_amdgcn_mfma_f32_16x16x32_bf16(qf[ks], b1, s1, 0, 0, 0);
                }
            }

            // ---- V(t) from global (L2/L3); latency hidden by softmax+barrier ----
            bf16x8 vb[8];
#pragma unroll
            for (int df = 0; df < 8; df++)
                vb[df] = *(const bf16x8*)
                    &Vb[(size_t)(wave * 128 + df * 16 + l16) * Tsz + kv0 + quad * 8];

            // ---- softmax + P write ----
            if (qact) {
                bool full = (kv0 + 31 <= qw);
#pragma unroll
                for (int r = 0; r < 4; r++) {
                    int rowg = qw + quad * 4 + r;
                    float p0 = __expf(fminf(s0[r], 40.f));
                    float p1 = __expf(fminf(s1[r], 40.f));
                    if (!full) {
                        if (kv0 + l16 > rowg) p0 = 0.f;
                        if (kv0 + 16 + l16 > rowg) p1 = 0.f;
                    }
                    lacc[r] += p0 + p1;
                    Pw[(quad * 4 + r) * 40 + l16] = f2bf(p0);
                    Pw[(quad * 4 + r) * 40 + 16 + l16] = f2bf(p1);
                }
            }
            __syncthreads();   // P visible block-wide; also drains K-DMA(t+1)

            // ---- PV: D-split across 4 waves; P from LDS, V from registers ----
#pragma unroll
            for (int rf = 0; rf < 4; rf++) {
                if (kv0 <= sr + rf * 16 + 15) {   // == wave rf's qact (skip stale P)
                    bf16x8 pa = *(const bf16x8*)
                        &smem[33280 + rf * 640 + l16 * 40 + quad * 8];
#pragma unroll
                    for (int df = 0; df < 8; df++)
                        acc[rf * 8 + df] = __builtin_amdgcn_mfma_f32_16x16x32_bf16(
                            pa, vb[df], acc[rf * 8 + df], 0, 0, 0);
                }
            }
            __syncthreads();   // protect P before next tile's writes
        }

        // epilogue: share per-row denominators via LDS (dedicated region)
        float* lsh = (float*)(smem + 35840);
#pragma unroll
        for (int r = 0; r < 4; r++) {
            float l = lacc[r];
            l += __shfl_xor(l, 1);
            l += __shfl_xor(l, 2);
            l += __shfl_xor(l, 4);
            l += __shfl_xor(l, 8);
            if (l16 == 0) lsh[wave * 16 + quad * 4 + r] = l;
        }
        __syncthreads();

#pragma unroll
        for (int rf = 0; rf < 4; rf++) {
#pragma unroll
            for (int r = 0; r < 4; r++) {
                float invl = 1.0f / lsh[rf * 16 + quad * 4 + r];
                int t = sr + rf * 16 + quad * 4 + r;
                float* op = &out[(size_t)(b * Tsz + t) * HDsz + h * Dsz
                                 + wave * 128 + l16];
#pragma unroll
                for (int df = 0; df < 8; df++)
                    op[df * 16] = acc[rf * 8 + df][r] * invl;
            }
        }
        // next pass's prologue barrier orders K/P reuse after these lsh reads
    }
}

extern "C" void kernel_launch(void* const* d_in, const int* in_sizes, int n_in,
                              void* d_out, int out_size, void* d_ws, size_t ws_size,
                              hipStream_t stream) {
    const float* query = (const float*)d_in[0];
    const float* value = (const float*)d_in[1];
    const float* Wq = (const float*)d_in[2];
    const float* bq = (const float*)d_in[3];
    const float* Wk = (const float*)d_in[4];
    const float* bk = (const float*)d_in[5];
    const float* Wv = (const float*)d_in[6];
    const float* bv = (const float*)d_in[7];
    float* out = (float*)d_out;

    char* ws = (char*)d_ws;
    short* Wt  = (short*)ws;                        // 12,582,912 B
    short* Xqb = (short*)(ws + 12582912);           //  8,388,608 B
    short* Xvb = (short*)(ws + 20971520);           //  8,388,608 B
    short* Qb  = (short*)(ws + 29360128);           // 67,108,864 B
    short* Kb  = (short*)(ws + 96468992);           // 67,108,864 B
    short* Vtb = (short*)(ws + 163577856);          // 67,108,864 B (end 230.7MB)

    (void)hipFuncSetAttribute((const void*)attn_kernel,
                        hipFuncAttributeMaxDynamicSharedMemorySize, 72192);

    xcast_kernel<<<8192, 256, 0, stream>>>(query, value, Xqb, Xvb);
    wtrans_kernel<<<dim3(16, 128, 3), dim3(32, 8), 0, stream>>>(Wq, Wk, Wv, Wt);
    proj_gemm_kernel<<<dim3(64, 32, 3), 256, 0, stream>>>(
        Xqb, Xvb, Wt, bq, bk, bv, Qb, Kb, Vtb);
    attn_kernel<<<dim3(512), dim3(256), 72192, stream>>>(Qb, Kb, Vtb, out);
}

// Round 5
// 534.274 us; speedup vs baseline: 3.5468x; 1.2528x over previous
//
#include <hip/hip_runtime.h>
#include <stdint.h>

#define Bsz 4
#define Tsz 2048
#define Dsz 512
#define Hsz 8
#define HDsz 4096
#define Msz 8192
#define SCALE 0.044194173824159216f

typedef __attribute__((ext_vector_type(8))) short bf16x8;
typedef __attribute__((ext_vector_type(4))) float f32x4;
typedef __attribute__((ext_vector_type(4))) short s16x4;

static __device__ __forceinline__ short f2bf(float x) {
    uint32_t b = __float_as_uint(x);
    b += 0x7fff + ((b >> 16) & 1);
    return (short)(b >> 16);
}

// ---------------- Kernel A: X fp32 -> bf16 cast (query & value) -------------
__global__ __launch_bounds__(256) void xcast_kernel(
    const float* __restrict__ Xq, const float* __restrict__ Xv,
    short* __restrict__ Oq, short* __restrict__ Ov)
{
    int idx = blockIdx.x * 256 + threadIdx.x;          // 0 .. 2*1048576-1
    const float* src = (idx < 1048576) ? Xq : Xv;
    short* dst = (idx < 1048576) ? Oq : Ov;
    int i = (idx < 1048576) ? idx : idx - 1048576;
    float4 v = *(const float4*)&src[(size_t)i * 4];
    s16x4 o;
    o.x = f2bf(v.x); o.y = f2bf(v.y); o.z = f2bf(v.z); o.w = f2bf(v.w);
    *(s16x4*)&dst[(size_t)i * 4] = o;
}

// ---------------- Kernel 0: weight transpose + bf16 convert -----------------
__global__ __launch_bounds__(256) void wtrans_kernel(
    const float* __restrict__ Wq, const float* __restrict__ Wk,
    const float* __restrict__ Wv, short* __restrict__ WtAll)
{
    const float* W = (blockIdx.z == 0) ? Wq : (blockIdx.z == 1) ? Wk : Wv;
    short* Wt = WtAll + (size_t)blockIdx.z * (size_t)HDsz * Dsz;
    __shared__ float tile[32][33];
    int tx = threadIdx.x, ty = threadIdx.y;
    int k0 = blockIdx.x * 32, n0 = blockIdx.y * 32;
    for (int i = 0; i < 4; i++)
        tile[ty + i * 8][tx] = W[(size_t)(k0 + ty + i * 8) * HDsz + n0 + tx];
    __syncthreads();
    for (int i = 0; i < 4; i++)
        Wt[(size_t)(n0 + ty + i * 8) * Dsz + k0 + tx] = f2bf(tile[tx][ty + i * 8]);
}

// ---------------- Kernel 1: fused QKV projection GEMM (round-1 config) ------
// A = Xbf [8192][512] bf16, B = Wt [4096][512] bf16. 128x128 tile, BK=32.
__global__ __launch_bounds__(256, 2) void proj_gemm_kernel(
    const short* __restrict__ Xqb, const short* __restrict__ Xvb,
    const short* __restrict__ WtAll, const float* __restrict__ bq,
    const float* __restrict__ bk, const float* __restrict__ bv,
    short* __restrict__ Qo, short* __restrict__ Ko, short* __restrict__ Vto)
{
    const int mode = blockIdx.z;
    const short* X = (mode == 0) ? Xqb : Xvb;
    const short* Wt = WtAll + (size_t)mode * (size_t)HDsz * Dsz;
    const float* bias = (mode == 0) ? bq : (mode == 1) ? bk : bv;
    const int m0 = blockIdx.x * 128, n0 = blockIdx.y * 128;

    __shared__ short sm[17408];

    const int tid = threadIdx.x;
    const int lane = tid & 63, wave = tid >> 6;
    const int quad = lane >> 4, l16 = lane & 15;
    const int wm = wave >> 1, wn = wave & 1;

    const int dmarow = lane >> 2;
    const int dmachunk = (lane & 3) ^ ((lane >> 3) & 3);
    const int rdsw = (quad ^ ((l16 >> 1) & 3)) * 8;   // fragment-read swizzle

    f32x4 acc[4][4];
    for (int i = 0; i < 4; i++)
        for (int j = 0; j < 4; j++)
            acc[i][j] = f32x4{0.f, 0.f, 0.f, 0.f};

#define STAGE(ksv, bufsel) do {                                                  \
        const int _ks = (ksv);                                                   \
        short* _A = sm + (bufsel) * 4096;                                        \
        short* _B = sm + 8192 + (bufsel) * 4096;                                 \
        for (int s = 0; s < 2; s++) {                                            \
            int c = wave * 2 + s;                                                \
            int row = c * 16 + dmarow;                                           \
            const short* ga = X + (size_t)(m0 + row) * Dsz + _ks + dmachunk * 8; \
            __builtin_amdgcn_global_load_lds(                                    \
                (const __attribute__((address_space(1))) void*)ga,               \
                (__attribute__((address_space(3))) void*)&_A[c * 512], 16, 0, 0);\
            const short* gb = Wt + (size_t)(n0 + row) * Dsz + _ks + dmachunk * 8;\
            __builtin_amdgcn_global_load_lds(                                    \
                (const __attribute__((address_space(1))) void*)gb,               \
                (__attribute__((address_space(3))) void*)&_B[c * 512], 16, 0, 0);\
        }                                                                        \
    } while (0)

    STAGE(0, 0);
    __syncthreads();

    for (int t = 0; t < 16; t++) {
        const int cur = t & 1;
        if (t < 15) STAGE((t + 1) * 32, cur ^ 1);   // prefetch overlaps compute
        const short* Ac = sm + cur * 4096;
        const short* Bc = sm + 8192 + cur * 4096;
        bf16x8 af[4], bfr[4];
        for (int i = 0; i < 4; i++)
            af[i] = *(const bf16x8*)&Ac[(wm * 64 + i * 16 + l16) * 32 + rdsw];
        for (int j = 0; j < 4; j++)
            bfr[j] = *(const bf16x8*)&Bc[(wn * 64 + j * 16 + l16) * 32 + rdsw];
        for (int i = 0; i < 4; i++)
            for (int j = 0; j < 4; j++)
                acc[i][j] = __builtin_amdgcn_mfma_f32_16x16x32_bf16(
                    af[i], bfr[j], acc[i][j], 0, 0, 0);
        __syncthreads();   // drains DMA(t+1) + protects buffer reuse
    }
#undef STAGE

    // ---- epilogue: stage C tile in LDS, then coalesced bf16x8 stores ----
    const int b = m0 >> 11, t0 = m0 & 2047;          // m-range is within one b
    const int h = n0 >> 9, d0 = n0 & 511;            // n-range is within one h
    const float scv = (mode == 0) ? SCALE : 1.0f;

    if (mode == 2) {
        // store transposed into LDS: C[d][t]
        for (int i = 0; i < 4; i++)
            for (int j = 0; j < 4; j++) {
                int c = wn * 64 + j * 16 + l16;
                float bb = bias[n0 + c];
                int rb = wm * 64 + i * 16 + quad * 4;
                for (int r = 0; r < 4; r++)
                    sm[c * 136 + rb + r] = f2bf(acc[i][j][r] + bb);
            }
    } else {
        // C[t][d]
        for (int i = 0; i < 4; i++)
            for (int j = 0; j < 4; j++) {
                int c = wn * 64 + j * 16 + l16;
                float bb = bias[n0 + c];
                int rb = wm * 64 + i * 16 + quad * 4;
                for (int r = 0; r < 4; r++)
                    sm[(rb + r) * 136 + c] = f2bf((acc[i][j][r] + bb) * scv);
            }
    }
    __syncthreads();

    if (mode == 2) {
        // Vt layout [bh][d][t]: contiguous along t
        size_t base = ((size_t)(b * Hsz + h) * Dsz + d0) * Tsz + t0;
        for (int k = 0; k < 8; k++) {
            int cid = k * 256 + tid;
            int c = cid >> 4, r8 = (cid & 15) * 8;
            *(bf16x8*)&Vto[base + (size_t)c * Tsz + r8] =
                *(const bf16x8*)&sm[c * 136 + r8];
        }
    } else {
        short* O = (mode == 0) ? Qo : Ko;
        size_t base = ((size_t)(b * Hsz + h) * Tsz + t0) * Dsz + d0;
        for (int k = 0; k < 8; k++) {
            int cid = k * 256 + tid;
            int r = cid >> 4, c8 = (cid & 15) * 8;
            *(bf16x8*)&O[base + (size_t)r * Dsz + c8] =
                *(const bf16x8*)&sm[r * 136 + c8];
        }
    }
}

// ---------------- Kernel 2: causal flash attention (v7: balanced pairs) -----
// Inner loop is EXACTLY the measured-best v2/v3 structure (8 waves, Br=128,
// Bc=32, double-buffered K & V in LDS, per-wave full-D PV, one barrier/tile).
// Outer change only: each block runs TWO q-tiles, qt=ib then qt=15-ib, so
// every block does 4(ib+1)+4(16-ib) = 68 kv-tiles. Grid = 8 pairs x 32 bh =
// 256 blocks = exactly 1/CU, balanced by construction (v2's round-robin
// pairing had worst-CU load 96 units -> 68 = x0.71).
// LDS 158720B: 2x K[32][520] + 2x V[512][40] + P 8x[16][40].
__global__ __launch_bounds__(512, 2) void attn_kernel(
    const short* __restrict__ Q, const short* __restrict__ K,
    const short* __restrict__ Vt, float* __restrict__ out)
{
    extern __shared__ short smem[];
    // layout: K0 @0, K1 @16640, V0 @33280, V1 @53760, P @74240 (shorts)

    const int bid = blockIdx.x;
    const int ib = bid >> 5;                           // 0..7 : pair index
    const int bh = bid & 31;
    const short* Qb = Q + (size_t)bh * Tsz * Dsz;
    const short* Kb = K + (size_t)bh * Tsz * Dsz;
    const short* Vb = Vt + (size_t)bh * Dsz * Tsz;

    const int tid = threadIdx.x;
    const int lane = tid & 63, wave = tid >> 6;
    const int quad = lane >> 4, l16 = lane & 15;
    short* Pw = smem + 74240 + wave * (16 * 40);
    const int vrow = tid >> 2, vch = tid & 3;          // V-stage mapping
    const int b = bh >> 3, h = bh & 7;

    for (int pass = 0; pass < 2; pass++) {
        const int qt = (pass == 0) ? ib : 15 - ib;
        const int q0 = qt * 128;
        const int qw = q0 + wave * 16;

        // Q fragments resident (16 ksteps x 8 bf16 = 64 VGPRs)
        bf16x8 qf[16];
        for (int ks = 0; ks < 16; ks++)
            qf[ks] = *(const bf16x8*)&Qb[(size_t)(qw + l16) * Dsz + ks * 32 + quad * 8];

        f32x4 acc[32];
        for (int dt = 0; dt < 32; dt++) acc[dt] = f32x4{0.f, 0.f, 0.f, 0.f};
        float lacc[4] = {0.f, 0.f, 0.f, 0.f};

        // prologue: stage tile 0 into buffer 0 (prev pass's last reads are
        // barrier-protected: final loop barrier precedes this)
        {
            short* Ks0 = smem;
            short* Vs0 = smem + 33280;
            for (int i = 0; i < 4; i++) {
                int r = wave * 4 + i;
                const short* gp = Kb + (size_t)r * Dsz + lane * 8;
                __builtin_amdgcn_global_load_lds(
                    (const __attribute__((address_space(1))) void*)gp,
                    (__attribute__((address_space(3))) void*)&Ks0[r * 520], 16, 0, 0);
            }
            for (int p = 0; p < 4; p++) {
                int row = p * 128 + vrow;
                bf16x8 v = *(const bf16x8*)&Vb[(size_t)row * Tsz + vch * 8];
                *(bf16x8*)&Vs0[row * 40 + vch * 8] = v;
            }
        }
        __syncthreads();

        const int nkv = 4 * (qt + 1);
        for (int kt = 0; kt < nkv; kt++) {
            const int kv0 = kt * 32;
            short* Ksc = smem + (kt & 1) * 16640;
            short* Vsc = smem + 33280 + (kt & 1) * 20480;
            const bool pref = (kt + 1 < nkv);

            // ---- prefetch tile t+1 (overlaps compute below) ----
            bf16x8 vreg[4];
            if (pref) {
                const int kvn = kv0 + 32;
                short* Ksn = smem + ((kt + 1) & 1) * 16640;
                for (int i = 0; i < 4; i++) {
                    int r = wave * 4 + i;
                    const short* gp = Kb + (size_t)(kvn + r) * Dsz + lane * 8;
                    __builtin_amdgcn_global_load_lds(
                        (const __attribute__((address_space(1))) void*)gp,
                        (__attribute__((address_space(3))) void*)&Ksn[r * 520], 16, 0, 0);
                }
                for (int p = 0; p < 4; p++) {
                    int row = p * 128 + vrow;
                    vreg[p] = *(const bf16x8*)&Vb[(size_t)row * Tsz + kvn + vch * 8];
                }
            }

            // ---- compute tile t ----
            if (kv0 <= qw + 15) {
                f32x4 s0 = f32x4{0.f, 0.f, 0.f, 0.f}, s1 = f32x4{0.f, 0.f, 0.f, 0.f};
                for (int ks = 0; ks < 16; ks++) {
                    bf16x8 b0 = *(const bf16x8*)&Ksc[l16 * 520 + ks * 32 + quad * 8];
                    bf16x8 b1 = *(const bf16x8*)&Ksc[(16 + l16) * 520 + ks * 32 + quad * 8];
                    s0 = __builtin_amdgcn_mfma_f32_16x16x32_bf16(qf[ks], b0, s0, 0, 0, 0);
                    s1 = __builtin_amdgcn_mfma_f32_16x16x32_bf16(qf[ks], b1, s1, 0, 0, 0);
                }
                bool full = (kv0 + 31 <= qw);
                for (int r = 0; r < 4; r++) {
                    int rowg = qw + quad * 4 + r;
                    float p0 = __expf(fminf(s0[r], 40.f));
                    float p1 = __expf(fminf(s1[r], 40.f));
                    if (!full) {
                        if (kv0 + l16 > rowg) p0 = 0.f;
                        if (kv0 + 16 + l16 > rowg) p1 = 0.f;
                    }
                    lacc[r] += p0 + p1;
                    Pw[(quad * 4 + r) * 40 + l16] = f2bf(p0);
                    Pw[(quad * 4 + r) * 40 + 16 + l16] = f2bf(p1);
                }
                bf16x8 pa = *(const bf16x8*)&Pw[l16 * 40 + quad * 8];
                for (int dt = 0; dt < 32; dt++) {
                    bf16x8 vb = *(const bf16x8*)&Vsc[(dt * 16 + l16) * 40 + quad * 8];
                    acc[dt] = __builtin_amdgcn_mfma_f32_16x16x32_bf16(pa, vb, acc[dt], 0, 0, 0);
                }
            }

            // ---- commit V(t+1) to its LDS buffer (safe: last read was t-1) ----
            if (pref) {
                short* Vsn = smem + 33280 + ((kt + 1) & 1) * 20480;
                for (int p = 0; p < 4; p++) {
                    int row = p * 128 + vrow;
                    *(bf16x8*)&Vsn[row * 40 + vch * 8] = vreg[p];
                }
            }
            __syncthreads();   // drains K-DMA(t+1) + V writes
        }

        // epilogue: reduce l over the 16 lanes holding each row, write O/l
        // (registers + shuffles only -> no barrier needed before next pass)
        float inv[4];
        for (int r = 0; r < 4; r++) {
            float l = lacc[r];
            l += __shfl_xor(l, 1);
            l += __shfl_xor(l, 2);
            l += __shfl_xor(l, 4);
            l += __shfl_xor(l, 8);
            inv[r] = 1.0f / l;
        }
        for (int dt = 0; dt < 32; dt++) {
            for (int r = 0; r < 4; r++) {
                int t = qw + quad * 4 + r;
                out[(size_t)(b * Tsz + t) * HDsz + h * Dsz + dt * 16 + l16] =
                    acc[dt][r] * inv[r];
            }
        }
    }
}

extern "C" void kernel_launch(void* const* d_in, const int* in_sizes, int n_in,
                              void* d_out, int out_size, void* d_ws, size_t ws_size,
                              hipStream_t stream) {
    const float* query = (const float*)d_in[0];
    const float* value = (const float*)d_in[1];
    const float* Wq = (const float*)d_in[2];
    const float* bq = (const float*)d_in[3];
    const float* Wk = (const float*)d_in[4];
    const float* bk = (const float*)d_in[5];
    const float* Wv = (const float*)d_in[6];
    const float* bv = (const float*)d_in[7];
    float* out = (float*)d_out;

    char* ws = (char*)d_ws;
    short* Wt  = (short*)ws;                        // 12,582,912 B
    short* Xqb = (short*)(ws + 12582912);           //  8,388,608 B
    short* Xvb = (short*)(ws + 20971520);           //  8,388,608 B
    short* Qb  = (short*)(ws + 29360128);           // 67,108,864 B
    short* Kb  = (short*)(ws + 96468992);           // 67,108,864 B
    short* Vtb = (short*)(ws + 163577856);          // 67,108,864 B (end 230.7MB)

    (void)hipFuncSetAttribute((const void*)attn_kernel,
                        hipFuncAttributeMaxDynamicSharedMemorySize, 158720);

    xcast_kernel<<<8192, 256, 0, stream>>>(query, value, Xqb, Xvb);
    wtrans_kernel<<<dim3(16, 128, 3), dim3(32, 8), 0, stream>>>(Wq, Wk, Wv, Wt);
    proj_gemm_kernel<<<dim3(64, 32, 3), 256, 0, stream>>>(
        Xqb, Xvb, Wt, bq, bk, bv, Qb, Kb, Vtb);
    attn_kernel<<<dim3(256), dim3(512), 158720, stream>>>(Qb, Kb, Vtb, out);
}